// Round 1
// baseline (60.521 us; speedup 1.0000x reference)
//
#include <hip/hip_runtime.h>
#include <hip/hip_bf16.h>

#define B 8
#define N 4096
#define CT 4               // candidate tiles per batch
#define TC (N / CT)        // 1024 candidates per tile
#define QBLK 64            // queries per block (1 wave)
#define BN (B * N)         // 32768 total queries

__device__ __forceinline__ float inf_f() { return __uint_as_float(0x7F800000u); }

// ---------------- init: ws min array = +inf ----------------
__global__ __launch_bounds__(256) void k_init(unsigned int* __restrict__ wmin) {
    int i = blockIdx.x * 256 + threadIdx.x;
    if (i < BN) wmin[i] = 0x7F800000u;
}

// ---------------- main: partial min d^2 per query over a candidate tile ----------------
__global__ __launch_bounds__(64) void k_min(const float* __restrict__ c,
                                            unsigned int* __restrict__ wmin) {
    __shared__ float4 cand[TC];   // 16 KB

    int blk = blockIdx.x;               // 0 .. B*(N/QBLK)*CT - 1 = 2047
    int ct  = blk & (CT - 1);
    int rem = blk >> 2;                 // log2(CT)=2
    int qt  = rem & (N / QBLK - 1);
    int b   = rem / (N / QBLK);

    const float* cb = c + (size_t)b * N * 3;
    int t = threadIdx.x;

    // stage candidate tile into LDS as float4 (x,y,z,0)
    int cbase = ct * TC;
    for (int k = t; k < TC; k += QBLK) {
        int j = cbase + k;
        cand[k] = make_float4(cb[3 * j], cb[3 * j + 1], cb[3 * j + 2], 0.0f);
    }
    __syncthreads();

    int   qi = qt * QBLK + t;
    float qx = cb[3 * qi], qy = cb[3 * qi + 1], qz = cb[3 * qi + 2];
    int   self = qi - cbase;            // relative self index; out of [0,TC) if not in tile

    const float INF = inf_f();
    float m0 = INF, m1 = INF, m2 = INF, m3 = INF;

    for (int k = 0; k < TC; k += 4) {
        float4 p0 = cand[k + 0];
        float4 p1 = cand[k + 1];
        float4 p2 = cand[k + 2];
        float4 p3 = cand[k + 3];

        float dx0 = qx - p0.x, dy0 = qy - p0.y, dz0 = qz - p0.z;
        float dx1 = qx - p1.x, dy1 = qy - p1.y, dz1 = qz - p1.z;
        float dx2 = qx - p2.x, dy2 = qy - p2.y, dz2 = qz - p2.z;
        float dx3 = qx - p3.x, dy3 = qy - p3.y, dz3 = qz - p3.z;

        float d0 = dx0 * dx0 + dy0 * dy0 + dz0 * dz0;
        float d1 = dx1 * dx1 + dy1 * dy1 + dz1 * dz1;
        float d2 = dx2 * dx2 + dy2 * dy2 + dz2 * dz2;
        float d3 = dx3 * dx3 + dy3 * dy3 + dz3 * dz3;

        d0 = (k + 0 == self) ? INF : d0;
        d1 = (k + 1 == self) ? INF : d1;
        d2 = (k + 2 == self) ? INF : d2;
        d3 = (k + 3 == self) ? INF : d3;

        m0 = fminf(m0, d0);
        m1 = fminf(m1, d1);
        m2 = fminf(m2, d2);
        m3 = fminf(m3, d3);
    }

    float m = fminf(fminf(m0, m1), fminf(m2, m3));
    atomicMin(&wmin[b * N + qi], __float_as_uint(m));   // d^2 >= 0 -> uint order == float order
}

// ---------------- final: loss = mean((sqrt(min_d2) - 0.2)^2) ----------------
__global__ __launch_bounds__(1024) void k_loss(const unsigned int* __restrict__ wmin,
                                               float* __restrict__ out) {
    double s = 0.0;
    for (int i = threadIdx.x; i < BN; i += 1024) {
        float d2 = __uint_as_float(wmin[i]);
        float d  = sqrtf(d2);
        float e  = d - 0.2f;
        s += (double)(e * e);
    }
    // wave reduce (64 lanes)
    for (int off = 32; off; off >>= 1) s += __shfl_down(s, off);

    __shared__ double sh[16];
    int wave = threadIdx.x >> 6;
    int lane = threadIdx.x & 63;
    if (lane == 0) sh[wave] = s;
    __syncthreads();
    if (threadIdx.x == 0) {
        double tot = 0.0;
        for (int w = 0; w < 16; ++w) tot += sh[w];
        out[0] = (float)(tot / (double)BN);
    }
}

// ---------------- fallback (no workspace): fused single kernel ----------------
__global__ __launch_bounds__(64) void k_single(const float* __restrict__ c,
                                               float* __restrict__ out) {
    __shared__ float sx[N], sy[N], sz[N];   // 48 KB
    int blk = blockIdx.x;                   // 0 .. B*(N/QBLK)-1 = 511
    int qt  = blk & (N / QBLK - 1);
    int b   = blk / (N / QBLK);
    const float* cb = c + (size_t)b * N * 3;
    int t = threadIdx.x;

    for (int k = t; k < N; k += QBLK) {
        sx[k] = cb[3 * k];
        sy[k] = cb[3 * k + 1];
        sz[k] = cb[3 * k + 2];
    }
    __syncthreads();

    int   qi = qt * QBLK + t;
    float qx = sx[qi], qy = sy[qi], qz = sz[qi];
    const float INF = inf_f();
    float m0 = INF, m1 = INF;
    for (int k = 0; k < N; k += 2) {
        float dx0 = qx - sx[k],     dy0 = qy - sy[k],     dz0 = qz - sz[k];
        float dx1 = qx - sx[k + 1], dy1 = qy - sy[k + 1], dz1 = qz - sz[k + 1];
        float d0 = dx0 * dx0 + dy0 * dy0 + dz0 * dz0;
        float d1 = dx1 * dx1 + dy1 * dy1 + dz1 * dz1;
        d0 = (k + 0 == qi) ? INF : d0;
        d1 = (k + 1 == qi) ? INF : d1;
        m0 = fminf(m0, d0);
        m1 = fminf(m1, d1);
    }
    float e = sqrtf(fminf(m0, m1)) - 0.2f;
    float v = e * e;
    for (int off = 32; off; off >>= 1) v += __shfl_down(v, off);
    if (t == 0) atomicAdd(out, v / (float)BN);
}

extern "C" void kernel_launch(void* const* d_in, const int* in_sizes, int n_in,
                              void* d_out, int out_size, void* d_ws, size_t ws_size,
                              hipStream_t stream) {
    const float* c   = (const float*)d_in[0];
    float*       out = (float*)d_out;

    if (ws_size >= (size_t)BN * sizeof(unsigned int)) {
        unsigned int* wmin = (unsigned int*)d_ws;
        k_init<<<(BN + 255) / 256, 256, 0, stream>>>(wmin);
        k_min<<<B * (N / QBLK) * CT, QBLK, 0, stream>>>(c, wmin);
        k_loss<<<1, 1024, 0, stream>>>(wmin, out);
    } else {
        hipMemsetAsync(d_out, 0, sizeof(float), stream);
        k_single<<<B * (N / QBLK), QBLK, 0, stream>>>(c, out);
    }
}

// Round 2
// 40.174 us; speedup vs baseline: 1.5065x; 1.5065x over previous
//
#include <hip/hip_runtime.h>
#include <hip/hip_bf16.h>

#define B 8
#define N 4096
#define BN (B * N)         // 32768 total queries

__device__ __forceinline__ float inf_f() { return __uint_as_float(0x7F800000u); }

// ---------------- init: ws min array = +inf ----------------
__global__ __launch_bounds__(256) void k_init(unsigned int* __restrict__ wmin) {
    int i = blockIdx.x * 256 + threadIdx.x;
    if (i < BN) wmin[i] = 0x7F800000u;
}

// ---------------- main: partial min d^2 ----------------
// Block (256 thr = 4 waves) handles 256 queries x 1024 candidates.
// Each wave: same 256 queries, its own 256-candidate chunk (scalar loads).
// Each thread: 4 consecutive queries in registers.
// Grid: B * (N/256) * (N/1024) = 8*16*4 = 512 blocks.
__global__ __launch_bounds__(256) void k_min(const float* __restrict__ c,
                                             unsigned int* __restrict__ wmin) {
    int blk = blockIdx.x;
    int cc  = blk & 3;          // candidate super-chunk (1024 cands)
    int rem = blk >> 2;
    int qc  = rem & 15;         // query chunk (256 queries)
    int b   = rem >> 4;         // batch

    int w = __builtin_amdgcn_readfirstlane((int)(threadIdx.x >> 6)); // wave id, forced SGPR
    int l = threadIdx.x & 63;

    const float* cb   = c + (size_t)b * N * 3;
    int qbase  = qc * 256;
    int cstart = cc * 1024 + w * 256;

    // load this thread's 4 queries (48 contiguous bytes, 16B-aligned)
    const float4* q4 = (const float4*)(cb + 3 * qbase + 12 * l);
    float4 a0 = q4[0], a1 = q4[1], a2 = q4[2];
    float qx0 = a0.x, qy0 = a0.y, qz0 = a0.z;
    float qx1 = a0.w, qy1 = a1.x, qz1 = a1.y;
    float qx2 = a1.z, qy2 = a1.w, qz2 = a2.x;
    float qx3 = a2.y, qy3 = a2.z, qz3 = a2.w;

    const float INF = inf_f();
    float m0 = INF, m1 = INF, m2 = INF, m3 = INF;

    const float* cp = cb + 3 * cstart;   // uniform pointer -> scalar loads

    if (cstart != qbase) {
        // off-diagonal: no self-mask needed
        #pragma unroll 4
        for (int k = 0; k < 256; ++k) {
            float cx = cp[3 * k], cy = cp[3 * k + 1], cz = cp[3 * k + 2];
            float dx, dy, dz, d;
            dx = qx0 - cx; dy = qy0 - cy; dz = qz0 - cz;
            d = dx * dx + dy * dy + dz * dz; m0 = fminf(m0, d);
            dx = qx1 - cx; dy = qy1 - cy; dz = qz1 - cz;
            d = dx * dx + dy * dy + dz * dz; m1 = fminf(m1, d);
            dx = qx2 - cx; dy = qy2 - cy; dz = qz2 - cz;
            d = dx * dx + dy * dy + dz * dz; m2 = fminf(m2, d);
            dx = qx3 - cx; dy = qy3 - cy; dz = qz3 - cz;
            d = dx * dx + dy * dy + dz * dz; m3 = fminf(m3, d);
        }
    } else {
        // diagonal chunk: relative self index of query j is 4*l+j
        int s = l << 2;
        #pragma unroll 4
        for (int k = 0; k < 256; ++k) {
            float cx = cp[3 * k], cy = cp[3 * k + 1], cz = cp[3 * k + 2];
            float dx, dy, dz, d;
            dx = qx0 - cx; dy = qy0 - cy; dz = qz0 - cz;
            d = dx * dx + dy * dy + dz * dz; d = (k == s + 0) ? INF : d; m0 = fminf(m0, d);
            dx = qx1 - cx; dy = qy1 - cy; dz = qz1 - cz;
            d = dx * dx + dy * dy + dz * dz; d = (k == s + 1) ? INF : d; m1 = fminf(m1, d);
            dx = qx2 - cx; dy = qy2 - cy; dz = qz2 - cz;
            d = dx * dx + dy * dy + dz * dz; d = (k == s + 2) ? INF : d; m2 = fminf(m2, d);
            dx = qx3 - cx; dy = qy3 - cy; dz = qz3 - cz;
            d = dx * dx + dy * dy + dz * dz; d = (k == s + 3) ? INF : d; m3 = fminf(m3, d);
        }
    }

    // cross-wave min reduce in LDS (float4 per thread, conflict-free)
    __shared__ float4 shm[3][64];
    if (w) shm[w - 1][l] = make_float4(m0, m1, m2, m3);
    __syncthreads();
    if (w == 0) {
        #pragma unroll
        for (int ww = 0; ww < 3; ++ww) {
            float4 v = shm[ww][l];
            m0 = fminf(m0, v.x); m1 = fminf(m1, v.y);
            m2 = fminf(m2, v.z); m3 = fminf(m3, v.w);
        }
        unsigned int* wp = wmin + b * N + qbase + (l << 2);
        atomicMin(wp + 0, __float_as_uint(m0));
        atomicMin(wp + 1, __float_as_uint(m1));
        atomicMin(wp + 2, __float_as_uint(m2));
        atomicMin(wp + 3, __float_as_uint(m3));
    }
}

// ---------------- final: loss = mean((sqrt(min_d2) - 0.2)^2) ----------------
__global__ __launch_bounds__(1024) void k_loss(const unsigned int* __restrict__ wmin,
                                               float* __restrict__ out) {
    const uint4* w4 = (const uint4*)wmin;      // 8192 uint4
    double s = 0.0;
    #pragma unroll
    for (int it = 0; it < 8; ++it) {
        uint4 v = w4[threadIdx.x + it * 1024];
        float e0 = sqrtf(__uint_as_float(v.x)) - 0.2f;
        float e1 = sqrtf(__uint_as_float(v.y)) - 0.2f;
        float e2 = sqrtf(__uint_as_float(v.z)) - 0.2f;
        float e3 = sqrtf(__uint_as_float(v.w)) - 0.2f;
        s += (double)(e0 * e0) + (double)(e1 * e1)
           + (double)(e2 * e2) + (double)(e3 * e3);
    }
    for (int off = 32; off; off >>= 1) s += __shfl_down(s, off);

    __shared__ double sh[16];
    int wave = threadIdx.x >> 6;
    int lane = threadIdx.x & 63;
    if (lane == 0) sh[wave] = s;
    __syncthreads();
    if (threadIdx.x == 0) {
        double tot = 0.0;
        for (int ww = 0; ww < 16; ++ww) tot += sh[ww];
        out[0] = (float)(tot / (double)BN);
    }
}

// ---------------- fallback (no workspace): fused single kernel ----------------
__global__ __launch_bounds__(64) void k_single(const float* __restrict__ c,
                                               float* __restrict__ out) {
    __shared__ float sx[N], sy[N], sz[N];   // 48 KB
    int blk = blockIdx.x;
    int qt  = blk & (N / 64 - 1);
    int b   = blk / (N / 64);
    const float* cb = c + (size_t)b * N * 3;
    int t = threadIdx.x;

    for (int k = t; k < N; k += 64) {
        sx[k] = cb[3 * k];
        sy[k] = cb[3 * k + 1];
        sz[k] = cb[3 * k + 2];
    }
    __syncthreads();

    int   qi = qt * 64 + t;
    float qx = sx[qi], qy = sy[qi], qz = sz[qi];
    const float INF = inf_f();
    float m0 = INF, m1 = INF;
    for (int k = 0; k < N; k += 2) {
        float dx0 = qx - sx[k],     dy0 = qy - sy[k],     dz0 = qz - sz[k];
        float dx1 = qx - sx[k + 1], dy1 = qy - sy[k + 1], dz1 = qz - sz[k + 1];
        float d0 = dx0 * dx0 + dy0 * dy0 + dz0 * dz0;
        float d1 = dx1 * dx1 + dy1 * dy1 + dz1 * dz1;
        d0 = (k + 0 == qi) ? INF : d0;
        d1 = (k + 1 == qi) ? INF : d1;
        m0 = fminf(m0, d0);
        m1 = fminf(m1, d1);
    }
    float e = sqrtf(fminf(m0, m1)) - 0.2f;
    float v = e * e;
    for (int off = 32; off; off >>= 1) v += __shfl_down(v, off);
    if (t == 0) atomicAdd(out, v / (float)BN);
}

extern "C" void kernel_launch(void* const* d_in, const int* in_sizes, int n_in,
                              void* d_out, int out_size, void* d_ws, size_t ws_size,
                              hipStream_t stream) {
    const float* c   = (const float*)d_in[0];
    float*       out = (float*)d_out;

    if (ws_size >= (size_t)BN * sizeof(unsigned int)) {
        unsigned int* wmin = (unsigned int*)d_ws;
        k_init<<<(BN + 255) / 256, 256, 0, stream>>>(wmin);
        k_min<<<B * (N / 256) * (N / 1024), 256, 0, stream>>>(c, wmin);
        k_loss<<<1, 1024, 0, stream>>>(wmin, out);
    } else {
        hipMemsetAsync(d_out, 0, sizeof(float), stream);
        k_single<<<B * (N / 64), 64, 0, stream>>>(c, out);
    }
}